// Round 4
// baseline (512.695 us; speedup 1.0000x reference)
//
#include <hip/hip_runtime.h>

// QECC statevector: 23 qubits, DIM = 2^23 amplitudes, N0 = 2 vectors per code.
// Gate ind0 acts on statevector bit p = 22 - ind0:  new_d = sum_b old_b * U[b,d].
//
// R4 split: k_low = idx bits 0..11 (gates q22..q11), 256-thr/32KB blocks (4-5
// blocks/CU to break R3's 2-block phase-locking). k_high = idx bits 12..22
// (gates q10..q0) + fused overlap dot, 512-thr/64KB blocks with a dot-layout
// LDS remap so c1 is read with float4 loads (R3 did 64 scalar scattered loads
// per thread -> vmcnt stall tail).
//
// Transposed intermediate (INTER path), per vector i:
//   idx = h*8192 + b*4096 + g*4 + e   (h: bits 13..22, b: bit 12, g: bits 2..11, e: bits 0..1)
//   W(i,idx) = i*DIM + g*8192 + h*8 + b*4 + e
// k_high block g reads W chunk [g*8192, g*8192+8192) contiguously.
// Verified: idx=5000000 -> (h=610,b=0,g=720,e=0) -> W=5903120 -> reconstructs 5000000.
#define DIM_ (1 << 23)
#define N0_ 2

// overlap accumulators {R00,I00,R01,I01,R10,I10,R11,I11}; zeroed by k_low block 0
__device__ float g_acc[8];

// LDS bank swizzle (bits 0,1 ^= bits 5,6 ; bits 2..4 ^= bits 7..9), bijective.
__device__ __forceinline__ int swz(int x) {
    return x ^ ((x >> 5) & 3) ^ (((x >> 7) & 7) << 2);
}

__device__ __forceinline__ void gload(const float* __restrict__ ur,
                                      const float* __restrict__ ui, int q,
                                      float2& u00, float2& u01, float2& u10, float2& u11) {
    u00 = make_float2(ur[q * 4 + 0], ui[q * 4 + 0]);
    u01 = make_float2(ur[q * 4 + 1], ui[q * 4 + 1]);
    u10 = make_float2(ur[q * 4 + 2], ui[q * 4 + 2]);
    u11 = make_float2(ur[q * 4 + 3], ui[q * 4 + 3]);
}

// out0 = u00*a0 + u10*a1 ; out1 = u01*a0 + u11*a1   (complex, einsum convention)
__device__ __forceinline__ void bfly(float2& a0, float2& a1,
                                     float2 u00, float2 u01, float2 u10, float2 u11) {
    float2 n0, n1;
    n0.x = a0.x * u00.x - a0.y * u00.y + a1.x * u10.x - a1.y * u10.y;
    n0.y = a0.x * u00.y + a0.y * u00.x + a1.x * u10.y + a1.y * u10.x;
    n1.x = a0.x * u01.x - a0.y * u01.y + a1.x * u11.x - a1.y * u11.y;
    n1.y = a0.x * u01.y + a0.y * u01.x + a1.x * u11.y + a1.y * u11.x;
    a0 = n0; a1 = n1;
}

// Butterfly all pairs of the 16-register file v[] differing in bit log2(S), gate Q.
#define BFLY16(S, Q)                                                           \
    do {                                                                       \
        float2 u00, u01, u10, u11;                                             \
        gload(ur, ui, (Q), u00, u01, u10, u11);                                \
        _Pragma("unroll")                                                      \
        for (int m0 = 0; m0 < 16; ++m0)                                        \
            if (!(m0 & (S))) bfly(v[m0], v[m0 + (S)], u00, u01, u10, u11);     \
    } while (0)

// ---------------------------------------------------------------------------
// K1: idx bits 0..11 (gates q22..q11). Block (C, iv) owns the contiguous
// 4096-complex chunk idx = C*4096 + l12. 256 thr x 16 complex regs, 32 KB LDS.
// Phases: A = l12 bits {0,1,10,11} -> q22,q21,q12,q11 (from float4 load layout)
//         B = l12 bits {2..5} -> q20..q17
//         C = l12 bits {6..9} -> q16..q13
// Store: transposed W layout (INTER) or identity planes (fallback, in-place
// safe since each block stores only its own chunk).
// ---------------------------------------------------------------------------
template <bool INTER>
__global__ __launch_bounds__(256, 5) void k_low(
    const float* __restrict__ inr, const float* __restrict__ ini,
    const float* __restrict__ ur, const float* __restrict__ ui,
    float2* __restrict__ outI, float* __restrict__ outR, float* __restrict__ outJ) {
    __shared__ float2 buf[4096];  // 32 KB
    const int t = threadIdx.x;
    const int C = blockIdx.x;   // chunk id, 0..2047
    const int iv = blockIdx.y;  // vector 0/1
    const int base = iv * DIM_ + (C << 12);

    if (C == 0 && iv == 0 && t < 8) g_acc[t] = 0.f;  // folded k_zero (runs before k_high)

    float2 v[16];
    // load: reg m = (k<<2)|j  <->  l12 = (k<<10)|(t<<2)|j   (1 KB contig per wave-instr)
#pragma unroll
    for (int k = 0; k < 4; ++k) {
        const int y = (k << 10) | (t << 2);
        const float4 re = *(const float4*)(inr + base + y);
        const float4 im = *(const float4*)(ini + base + y);
        v[k * 4 + 0] = make_float2(re.x, im.x);
        v[k * 4 + 1] = make_float2(re.y, im.y);
        v[k * 4 + 2] = make_float2(re.z, im.z);
        v[k * 4 + 3] = make_float2(re.w, im.w);
    }
    // Phase A: m0=l0->q22, m1=l1->q21, m2=l10->q12, m3=l11->q11
    BFLY16(1, 22);
    BFLY16(2, 21);
    BFLY16(4, 12);
    BFLY16(8, 11);
#pragma unroll
    for (int m = 0; m < 16; ++m)
        buf[swz(((m >> 2) << 10) | (t << 2) | (m & 3))] = v[m];
    __syncthreads();
    // Phase B: m = l12 bits 2..5 ; x = (t&3) | (m<<2) | ((t>>2)<<6)
#pragma unroll
    for (int m = 0; m < 16; ++m)
        v[m] = buf[swz((t & 3) | (m << 2) | ((t >> 2) << 6))];
    BFLY16(1, 20);
    BFLY16(2, 19);
    BFLY16(4, 18);
    BFLY16(8, 17);
#pragma unroll
    for (int m = 0; m < 16; ++m)
        buf[swz((t & 3) | (m << 2) | ((t >> 2) << 6))] = v[m];  // same slots: no race
    __syncthreads();
    // Phase C: m = l12 bits 6..9 ; x = (t&63) | (m<<6) | ((t>>6)<<10)
#pragma unroll
    for (int m = 0; m < 16; ++m)
        v[m] = buf[swz((t & 63) | (m << 6) | ((t >> 6) << 10))];
    BFLY16(1, 16);
    BFLY16(2, 15);
    BFLY16(4, 14);
    BFLY16(8, 13);
#pragma unroll
    for (int m = 0; m < 16; ++m)
        buf[swz((t & 63) | (m << 6) | ((t >> 6) << 10))] = v[m];
    __syncthreads();
    // Store: pairs (l12, l12+1) -> one float4.
#pragma unroll
    for (int r = 0; r < 8; ++r) {
        const int l12 = (r << 9) | (t << 1);
        const float2 a = buf[swz(l12)];
        const float2 b = buf[swz(l12 | 1)];
        if (INTER) {
            // W = ((l12>>2)<<13) | ((C>>1)<<3) | ((C&1)<<2) | (l12&3)
            const int o = ((l12 >> 2) << 13) | ((C >> 1) << 3) | ((C & 1) << 2) | (l12 & 3);
            *(float4*)(outI + iv * DIM_ + o) = make_float4(a.x, a.y, b.x, b.y);
        } else {
            *(float2*)(outR + base + l12) = make_float2(a.x, b.x);
            *(float2*)(outJ + base + l12) = make_float2(a.y, b.y);
        }
    }
}

// ---------------------------------------------------------------------------
// One 11-bit high-pass for vector iv. Local y = h*8 + b*4 + e (13 bits).
// Phases: A = y bits {11,12} = h8,h9 -> q1,q0 (from load layout)
//         B = y bits {3..6}  = h0..h3 -> q9..q6
//         C = y bits {7..10} = h4..h7 -> q5..q2
// Then dot-layout remap (thread t owns y = 16t..16t+15) and gate q10 on
// in-thread pairs (j, j^4). Leaves d[] in dot layout. No trailing barrier.
// ---------------------------------------------------------------------------
template <bool INTER>
__device__ __forceinline__ void high_pass(
    float2 (&d)[16], float2* buf, const int t, const int g, const int iv,
    const float2* __restrict__ wsI, const float* __restrict__ wsR,
    const float* __restrict__ wsJ,
    const float* __restrict__ ur, const float* __restrict__ ui) {
    float2 v[16];
    // load: reg m = (k<<2)|j <-> y = (k<<11)|(t<<2)|j
    if constexpr (INTER) {
        const float4* wsv = (const float4*)(wsI + iv * DIM_ + (g << 13));
#pragma unroll
        for (int k = 0; k < 4; ++k)
#pragma unroll
            for (int jh = 0; jh < 2; ++jh) {
                const float4 f = wsv[(k << 10) | (t << 1) | jh];
                v[k * 4 + jh * 2 + 0] = make_float2(f.x, f.y);
                v[k * 4 + jh * 2 + 1] = make_float2(f.z, f.w);
            }
    } else {
        // identity-layout fallback: idx = (y>>2)*4096 + g*4 + (y&3); y>>2 = (k<<9)|t
#pragma unroll
        for (int k = 0; k < 4; ++k) {
            const int a = (((k << 9) | t) << 12) | (g << 2);
            const float4 re = *(const float4*)(wsR + iv * DIM_ + a);
            const float4 im = *(const float4*)(wsJ + iv * DIM_ + a);
            v[k * 4 + 0] = make_float2(re.x, im.x);
            v[k * 4 + 1] = make_float2(re.y, im.y);
            v[k * 4 + 2] = make_float2(re.z, im.z);
            v[k * 4 + 3] = make_float2(re.w, im.w);
        }
    }
    // Phase A: reg m2,m3 = y bits 11,12 = h8,h9 -> q1,q0
    BFLY16(4, 1);
    BFLY16(8, 0);
#pragma unroll
    for (int m = 0; m < 16; ++m)
        buf[swz(((m >> 2) << 11) | (t << 2) | (m & 3))] = v[m];
    __syncthreads();
    // Phase B: m = y bits 3..6 ; x = (t&7) | (m<<3) | ((t>>3)<<7)
#pragma unroll
    for (int m = 0; m < 16; ++m)
        v[m] = buf[swz((t & 7) | (m << 3) | ((t >> 3) << 7))];
    BFLY16(1, 9);
    BFLY16(2, 8);
    BFLY16(4, 7);
    BFLY16(8, 6);
#pragma unroll
    for (int m = 0; m < 16; ++m)
        buf[swz((t & 7) | (m << 3) | ((t >> 3) << 7))] = v[m];  // same slots
    __syncthreads();
    // Phase C: m = y bits 7..10 ; x = (t&127) | (m<<7) | ((t>>7)<<11)
#pragma unroll
    for (int m = 0; m < 16; ++m)
        v[m] = buf[swz((t & 127) | (m << 7) | ((t >> 7) << 11))];
    BFLY16(1, 5);
    BFLY16(2, 4);
    BFLY16(4, 3);
    BFLY16(8, 2);
    // Stage to dot layout
#pragma unroll
    for (int m = 0; m < 16; ++m)
        buf[swz((t & 127) | (m << 7) | ((t >> 7) << 11))] = v[m];
    __syncthreads();
    // Dot-layout read: thread owns y = 16t+j (rows 4t..4t+3, e = j&3)
#pragma unroll
    for (int j = 0; j < 16; ++j)
        d[j] = buf[swz((t << 4) | j)];
    // Gate q10 (idx bit 12 = y bit 2): in-thread pairs (j, j^4)
    {
        float2 u00, u01, u10, u11;
        gload(ur, ui, 10, u00, u01, u10, u11);
#pragma unroll
        for (int j = 0; j < 16; ++j)
            if (!(j & 4)) bfly(d[j], d[j | 4], u00, u01, u10, u11);
    }
}

// ---------------------------------------------------------------------------
// K2: idx bits 12..22 (gates q10..q0) + fused overlap dot. Block g (1024)
// owns idx with bits 2..11 == g. Transforms iv=0 -> d0, iv=1 -> d1, then dots
// against c1 with float4 loads: idx = (y>>2)*4096 + g*4 + (y&3), thread t owns
// rows R = 4t..4t+3 (row stride 4096 floats, 16 B used per row).
// ---------------------------------------------------------------------------
template <bool INTER>
__global__ __launch_bounds__(512, 2) void k_high(
    const float2* __restrict__ wsI, const float* __restrict__ wsR, const float* __restrict__ wsJ,
    const float* __restrict__ c1r, const float* __restrict__ c1i,
    const float* __restrict__ ur, const float* __restrict__ ui) {
    __shared__ float2 buf[8192];  // 64 KB; reused as reduction scratch
    const int t = threadIdx.x;
    const int g = blockIdx.x;

    float2 d0[16], d1[16];
    high_pass<INTER>(d0, buf, t, g, 0, wsI, wsR, wsJ, ur, ui);
    __syncthreads();  // buf handoff
    high_pass<INTER>(d1, buf, t, g, 1, wsI, wsR, wsJ, ur, ui);

    float acc[8];
#pragma unroll
    for (int k = 0; k < 8; ++k) acc[k] = 0.f;
    const int col = g << 2;
#pragma unroll
    for (int jv = 0; jv < 2; ++jv) {
        const float* __restrict__ pr = c1r + jv * DIM_;
        const float* __restrict__ pi = c1i + jv * DIM_;
#pragma unroll
        for (int w = 0; w < 4; ++w) {
            const int R = (t << 2) | w;
            const float4 yr = *(const float4*)(pr + ((long long)R << 12) + col);
            const float4 yi = *(const float4*)(pi + ((long long)R << 12) + col);
#pragma unroll
            for (int e = 0; e < 4; ++e) {
                const int j = (w << 2) | e;
                const float ar = ((const float*)&yr)[e];
                const float ai = ((const float*)&yi)[e];
                acc[jv * 2 + 0] += d0[j].x * ar + d0[j].y * ai;
                acc[jv * 2 + 1] += d0[j].x * ai - d0[j].y * ar;
                acc[jv * 2 + 4] += d1[j].x * ar + d1[j].y * ai;
                acc[jv * 2 + 5] += d1[j].x * ai - d1[j].y * ar;
            }
        }
    }
    // acc layout: [i*4 + jv*2 + {Re,Im}] = {R00,I00,R01,I01,R10,I10,R11,I11} ✓

    // wave (64) shuffle reduce -> cross-wave LDS -> one atomic per block
#pragma unroll
    for (int k = 0; k < 8; ++k)
#pragma unroll
        for (int off = 32; off > 0; off >>= 1)
            acc[k] += __shfl_down(acc[k], off, 64);
    __syncthreads();  // all waves past buf reads before reuse as scratch
    float* red = (float*)buf;
    const int wave = t >> 6, lane = t & 63;
    if (lane == 0) {
#pragma unroll
        for (int k = 0; k < 8; ++k) red[wave * 8 + k] = acc[k];
    }
    __syncthreads();
    if (t < 8) {
        float s = 0.f;
#pragma unroll
        for (int w = 0; w < 8; ++w) s += red[w * 8 + t];
        atomicAdd(&g_acc[t], s);
    }
}

__global__ void k_fin(float* __restrict__ out) {
    if (threadIdx.x == 0) {
        float s = 0.f;
#pragma unroll
        for (int k = 0; k < 4; ++k)
            s += g_acc[2 * k] * g_acc[2 * k] + g_acc[2 * k + 1] * g_acc[2 * k + 1];
        out[0] = (float)N0_ - s;
    }
}

extern "C" void kernel_launch(void* const* d_in, const int* in_sizes, int n_in,
                              void* d_out, int out_size, void* d_ws, size_t ws_size,
                              hipStream_t stream) {
    const float* c0r = (const float*)d_in[0];
    const float* c0i = (const float*)d_in[1];
    const float* c1r = (const float*)d_in[2];
    const float* c1i = (const float*)d_in[3];
    const float* ur  = (const float*)d_in[4];
    const float* ui  = (const float*)d_in[5];
    float* out = (float*)d_out;

    const size_t need = (size_t)N0_ * DIM_ * sizeof(float2);  // 128 MB intermediate
    dim3 g1(2048, N0_);
    if (d_ws != nullptr && ws_size >= need) {
        float2* wsI = (float2*)d_ws;
        k_low<true><<<g1, 256, 0, stream>>>(c0r, c0i, ur, ui, wsI, nullptr, nullptr);
        k_high<true><<<1024, 512, 0, stream>>>(wsI, nullptr, nullptr, c1r, c1i, ur, ui);
    } else {
        // fallback: identity layout, in place into code0 planes (harness restores
        // d_in from pristine copies before every timed launch)
        float* oR = (float*)c0r;
        float* oJ = (float*)c0i;
        k_low<false><<<g1, 256, 0, stream>>>(c0r, c0i, ur, ui, nullptr, oR, oJ);
        k_high<false><<<1024, 512, 0, stream>>>(nullptr, oR, oJ, c1r, c1i, ur, ui);
    }
    k_fin<<<1, 64, 0, stream>>>(out);
}